// Round 1
// baseline (17780.927 us; speedup 1.0000x reference)
//
#include <hip/hip_runtime.h>
#include <cstdint>
#include <cstddef>

// Problem constants: B=8, C_in=256, H=W=128
#define HW 16384

// ---------------------------------------------------------------------------
// conv3x3 SAME + BN affine (+optional ReLU), fp32 direct.
// Block: 256 threads. Spatial tile 32x32 (2x2 per thread), OCB=8 oc per block,
// ICB=4 input channels staged in LDS per chunk.
// Grid: x = 16 tiles (4x4 of 32x32), y = Cout/8, z = batch(8)
// ---------------------------------------------------------------------------
template<bool RELU>
__global__ __launch_bounds__(256)
void conv3x3_k(const float* __restrict__ in, const float* __restrict__ wgt,
               const float* __restrict__ sc, const float* __restrict__ bi,
               float* __restrict__ out, int Cin)
{
    __shared__ float smem[4][34][36];   // +2 pad cols keeps float2 reads 8B aligned
    const int tid  = threadIdx.x;
    const int ty   = tid >> 4;          // 0..15
    const int tx   = tid & 15;          // 0..15
    const int tile = blockIdx.x;        // 0..15
    const int th0  = (tile >> 2) * 32;
    const int tw0  = (tile & 3) * 32;
    const int oc0  = blockIdx.y * 8;
    const int n    = blockIdx.z;
    const int Cout = gridDim.y * 8;

    float acc[8][2][2];
    #pragma unroll
    for (int o = 0; o < 8; ++o) {
        acc[o][0][0] = 0.f; acc[o][0][1] = 0.f;
        acc[o][1][0] = 0.f; acc[o][1][1] = 0.f;
    }

    const float* wb = wgt + (size_t)oc0 * Cin * 9;

    for (int c0 = 0; c0 < Cin; c0 += 4) {
        __syncthreads();
        // stage 4 channels of 34x34 halo patch (zero border)
        for (int idx = tid; idx < 4 * 34 * 34; idx += 256) {
            int c  = idx / (34 * 34);
            int p  = idx - c * (34 * 34);
            int py = p / 34;
            int px = p - py * 34;
            int gh = th0 + py - 1;
            int gw = tw0 + px - 1;
            float v = 0.f;
            if ((unsigned)gh < 128u && (unsigned)gw < 128u)
                v = in[(((size_t)n * Cin + (c0 + c)) << 14) + (gh << 7) + gw];
            smem[c][py][px] = v;
        }
        __syncthreads();
        #pragma unroll
        for (int c = 0; c < 4; ++c) {
            // weights are block-uniform -> scalar loads
            float w9[8][9];
            #pragma unroll
            for (int o = 0; o < 8; ++o) {
                const float* wp = wb + ((size_t)o * Cin + (c0 + c)) * 9;
                #pragma unroll
                for (int j = 0; j < 9; ++j) w9[o][j] = wp[j];
            }
            // 4x4 input window for the 2x2 micro-tile
            float xv[4][4];
            #pragma unroll
            for (int rr = 0; rr < 4; ++rr) {
                float2 a = *(const float2*)&smem[c][2 * ty + rr][2 * tx];
                float2 b = *(const float2*)&smem[c][2 * ty + rr][2 * tx + 2];
                xv[rr][0] = a.x; xv[rr][1] = a.y; xv[rr][2] = b.x; xv[rr][3] = b.y;
            }
            #pragma unroll
            for (int o = 0; o < 8; ++o) {
                #pragma unroll
                for (int r = 0; r < 2; ++r) {
                    #pragma unroll
                    for (int s = 0; s < 2; ++s) {
                        float a = acc[o][r][s];
                        #pragma unroll
                        for (int ky = 0; ky < 3; ++ky)
                            #pragma unroll
                            for (int kx = 0; kx < 3; ++kx)
                                a += xv[r + ky][s + kx] * w9[o][ky * 3 + kx];
                        acc[o][r][s] = a;
                    }
                }
            }
        }
    }
    // epilogue: y = conv * s + b (+relu)
    #pragma unroll
    for (int o = 0; o < 8; ++o) {
        float s = sc[oc0 + o], bb = bi[oc0 + o];
        #pragma unroll
        for (int r = 0; r < 2; ++r) {
            #pragma unroll
            for (int ss2 = 0; ss2 < 2; ++ss2) {
                float y = acc[o][r][ss2] * s + bb;
                if (RELU) y = fmaxf(y, 0.f);
                int h = th0 + 2 * ty + r;
                int w = tw0 + 2 * tx + ss2;
                out[(((size_t)n * Cout + oc0 + o) << 14) + (h << 7) + w] = y;
            }
        }
    }
}

// ---------------------------------------------------------------------------
// in-place cummax along H. One block per (n,c) plane, thread = one column.
// ---------------------------------------------------------------------------
__global__ __launch_bounds__(128)
void pool_h_k(float* __restrict__ p, int reverse)
{
    const size_t base = (size_t)blockIdx.x << 14;
    const int w = threadIdx.x;
    float m = -3.402823466e+38f;
    if (reverse) {
        #pragma unroll 4
        for (int h = 127; h >= 0; --h) {
            size_t i = base + (h << 7) + w;
            m = fmaxf(m, p[i]);
            p[i] = m;
        }
    } else {
        #pragma unroll 4
        for (int h = 0; h < 128; ++h) {
            size_t i = base + (h << 7) + w;
            m = fmaxf(m, p[i]);
            p[i] = m;
        }
    }
}

// ---------------------------------------------------------------------------
// cummax along W of lsrc (optionally reversed) + add into tp_dst (in place):
// tp_dst[row] = cummaxW(lsrc)[row] + tp_dst[row].   One block per row.
// ---------------------------------------------------------------------------
__global__ __launch_bounds__(128)
void pool_w_add_k(const float* __restrict__ lsrc, float* tp_dst, int reverse)
{
    __shared__ float sm[128];
    const size_t base = (size_t)blockIdx.x << 7;
    const int tid = threadIdx.x;
    const int j = reverse ? (127 - tid) : tid;
    sm[tid] = lsrc[base + j];
    __syncthreads();
    #pragma unroll
    for (int off = 1; off < 128; off <<= 1) {
        float v = sm[tid];
        if (tid >= off) v = fmaxf(v, sm[tid - off]);
        __syncthreads();
        sm[tid] = v;
        __syncthreads();
    }
    float u = sm[tid] + tp_dst[base + j];
    tp_dst[base + j] = u;
}

// ---------------------------------------------------------------------------
// conv1x1 + BN affine, fused residual add + ReLU:
// inout = max(inout + (x (*) w)*s + b, 0).  OCB=16, 1 px/thread.
// Grid: x = 64 px-tiles of 256, y = 16 (oc/16), z = 8
// ---------------------------------------------------------------------------
__global__ __launch_bounds__(256)
void conv1x1_k(const float* __restrict__ x, const float* __restrict__ w1,
               const float* __restrict__ sc, const float* __restrict__ bi,
               float* __restrict__ inout)
{
    const int tid = threadIdx.x;
    const int px  = blockIdx.x * 256 + tid;
    const int oc0 = blockIdx.y * 16;
    const int n   = blockIdx.z;
    float acc[16];
    #pragma unroll
    for (int o = 0; o < 16; ++o) acc[o] = 0.f;
    const float* xb = x + ((size_t)n * 256 << 14);
    #pragma unroll 4
    for (int ic = 0; ic < 256; ++ic) {
        float xv = xb[((size_t)ic << 14) + px];
        #pragma unroll
        for (int o = 0; o < 16; ++o)
            acc[o] += xv * w1[(((size_t)(oc0 + o)) << 8) + ic];
    }
    #pragma unroll
    for (int o = 0; o < 16; ++o) {
        float y = acc[o] * sc[oc0 + o] + bi[oc0 + o];
        size_t oidx = (((size_t)n * 256 + oc0 + o) << 14) + px;
        float pv = inout[oidx];
        inout[oidx] = fmaxf(pv + y, 0.f);
    }
}

// ---------------------------------------------------------------------------
extern "C" void kernel_launch(void* const* d_in, const int* in_sizes, int n_in,
                              void* d_out, int out_size, void* d_ws, size_t ws_size,
                              hipStream_t stream)
{
    const float* x     = (const float*)d_in[0];
    const float* w_t   = (const float*)d_in[1];
    const float* s_t   = (const float*)d_in[2];
    const float* b_t   = (const float*)d_in[3];
    const float* w_l   = (const float*)d_in[4];
    const float* s_l   = (const float*)d_in[5];
    const float* b_l   = (const float*)d_in[6];
    const float* w_b   = (const float*)d_in[7];
    const float* s_b   = (const float*)d_in[8];
    const float* b_b   = (const float*)d_in[9];
    const float* w_r   = (const float*)d_in[10];
    const float* s_r   = (const float*)d_in[11];
    const float* b_r   = (const float*)d_in[12];
    const float* w_tl3 = (const float*)d_in[13];
    const float* s_tl3 = (const float*)d_in[14];
    const float* b_tl3 = (const float*)d_in[15];
    const float* w_br3 = (const float*)d_in[16];
    const float* s_br3 = (const float*)d_in[17];
    const float* b_br3 = (const float*)d_in[18];
    const float* w_tl1 = (const float*)d_in[19];
    const float* s_tl1 = (const float*)d_in[20];
    const float* b_tl1 = (const float*)d_in[21];
    const float* w_br1 = (const float*)d_in[22];
    const float* s_br1 = (const float*)d_in[23];
    const float* b_br1 = (const float*)d_in[24];
    const float* w_tlo = (const float*)d_in[25];
    const float* s_tlo = (const float*)d_in[26];
    const float* b_tlo = (const float*)d_in[27];
    const float* w_bro = (const float*)d_in[28];
    const float* s_bro = (const float*)d_in[29];
    const float* b_bro = (const float*)d_in[30];

    float* out = (float*)d_out;
    const size_t N1 = (size_t)8 * 128 * HW;          // elems of one 128-ch tensor
    float* t  = (float*)d_ws;                        // later holds u1 = tp+lp
    float* bb = t + N1;                              // later holds u2 = bp+rp
    float* lr = bb + N1;                             // l at lr, r at lr+N1; later br (256ch)
    float* l  = lr;
    float* r  = lr + N1;
    float* tlbuf = out + 2 * N1;                     // d_out 2nd half: staging for tl

    dim3 blk(256);

    // stage A: four conv3x3+bn+relu from x (Cin=256, Cout=128)
    conv3x3_k<true><<<dim3(16, 16, 8), blk, 0, stream>>>(x, w_t, s_t, b_t, t,  256);
    conv3x3_k<true><<<dim3(16, 16, 8), blk, 0, stream>>>(x, w_l, s_l, b_l, l,  256);
    conv3x3_k<true><<<dim3(16, 16, 8), blk, 0, stream>>>(x, w_b, s_b, b_b, bb, 256);
    conv3x3_k<true><<<dim3(16, 16, 8), blk, 0, stream>>>(x, w_r, s_r, b_r, r,  256);

    // directional pools: t -> tp (rev H), b -> bp (fwd H), then
    // t = u1 = tp + revcummaxW(l), b = u2 = bp + cummaxW(r)
    pool_h_k<<<dim3(1024), dim3(128), 0, stream>>>(t, 1);
    pool_h_k<<<dim3(1024), dim3(128), 0, stream>>>(bb, 0);
    pool_w_add_k<<<dim3(131072), dim3(128), 0, stream>>>(l, t, 1);
    pool_w_add_k<<<dim3(131072), dim3(128), 0, stream>>>(r, bb, 0);

    // tl chain: P_tl = convbn(u1, tl3, no relu) -> tlbuf (d_out 2nd half)
    conv3x3_k<false><<<dim3(16, 32, 8), blk, 0, stream>>>(t, w_tl3, s_tl3, b_tl3, tlbuf, 128);
    // tl = relu(P_tl + convbn(x, tl1))  (in place)
    conv1x1_k<<<dim3(64, 16, 8), blk, 0, stream>>>(x, w_tl1, s_tl1, b_tl1, tlbuf);

    // br chain: P_br -> lr region (l,r no longer needed)
    conv3x3_k<false><<<dim3(16, 32, 8), blk, 0, stream>>>(bb, w_br3, s_br3, b_br3, lr, 128);
    conv1x1_k<<<dim3(64, 16, 8), blk, 0, stream>>>(x, w_br1, s_br1, b_br1, lr);

    // outputs: out_tl = convbn(tl, tlo, relu) -> d_out 1st half (reads 2nd half)
    conv3x3_k<true><<<dim3(16, 32, 8), blk, 0, stream>>>(tlbuf, w_tlo, s_tlo, b_tlo, out, 256);
    // out_br = convbn(br, bro, relu) -> d_out 2nd half (tl staging dead now)
    conv3x3_k<true><<<dim3(16, 32, 8), blk, 0, stream>>>(lr, w_bro, s_bro, b_bro, out + 2 * N1, 256);
}

// Round 3
// 2042.543 us; speedup vs baseline: 8.7053x; 8.7053x over previous
//
#include <hip/hip_runtime.h>
#include <cstdint>
#include <cstddef>

// B=8, C=256/128, H=W=128. Padded NHWC bf16 tensors: [n][130][130][C], pad ring = 0.
// elem(n,h,w,c) = ((n*130 + h+1)*130 + (w+1))*C + c

typedef float  f32x4 __attribute__((ext_vector_type(4)));
typedef float  f4v   __attribute__((ext_vector_type(4)));
typedef short  s16x8 __attribute__((ext_vector_type(8)));
typedef unsigned short u16x4 __attribute__((ext_vector_type(4)));

__device__ __forceinline__ float bf2f(unsigned short u) {
    unsigned x = ((unsigned)u) << 16;
    return __builtin_bit_cast(float, x);
}
__device__ __forceinline__ unsigned short f2bf(float f) {
    unsigned u = __builtin_bit_cast(unsigned, f);
    unsigned r = (u + 0x7fffu + ((u >> 16) & 1u)) >> 16;
    return (unsigned short)r;
}

#define GL_LDS(gp, lp) __builtin_amdgcn_global_load_lds( \
    (const __attribute__((address_space(1))) unsigned int*)(const void*)(gp), \
    (__attribute__((address_space(3))) unsigned int*)(void*)(lp), 16, 0, 0)

// ---------------------------------------------------------------------------
// conv3x3 + BN affine (+opt ReLU), bf16 MFMA implicit GEMM.
// block 256 thr = 4 waves; tile = 128 oc x 128 pix (one image row); K = CIN*9.
// grid (COUT/128, 128 h, 8 n)
// ---------------------------------------------------------------------------
template<int CIN, int COUT, bool RELU, bool OUTF32>
__global__ __launch_bounds__(256, 2)
void conv3_mfma(const unsigned short* __restrict__ in,
                const unsigned short* __restrict__ wpk,
                const float* __restrict__ sc, const float* __restrict__ bi,
                void* __restrict__ outv)
{
    __shared__ unsigned short lds[3 * 4224];     // [3 rows][132 ps][32 ic], row stride 8448 B
    const int tid  = threadIdx.x;
    const int h    = blockIdx.y;
    const int n    = blockIdx.z;
    const int lane = tid & 63;
    const int wv   = tid >> 6;
    const int c    = lane & 15;
    const int g    = lane >> 4;
    const int pixbase = (wv >> 1) * 64;
    const int ocbase  = blockIdx.x * 128 + (wv & 1) * 64;
    const int ocf0    = blockIdx.x * 8 + (wv & 1) * 4;   // first oc-frag index (global)
    const int n130h   = n * 130 + h;

    // B-frag LDS byte addresses [p][kx] (ky term added as compile-time offset)
    int addr12[12];
    #pragma unroll
    for (int p = 0; p < 4; ++p)
        #pragma unroll
        for (int kx = 0; kx < 3; ++kx) {
            int ps = pixbase + 16 * p + c + kx;           // padded col index
            addr12[p * 3 + kx] = ps * 64 + ((g ^ ((ps >> 1) & 3)) << 4);
        }

    // halo columns ps=0 and ps=129 are always zero (image border) - write once
    if (tid < 24) {
        int rr = tid >> 3, side = (tid >> 2) & 1, q = tid & 3;
        int ps = side ? 129 : 0;
        uint4 z; z.x = 0; z.y = 0; z.z = 0; z.w = 0;
        *(uint4*)((char*)lds + rr * 8448 + ps * 64 + q * 16) = z;
    }

    f32x4 acc[4][4];
    #pragma unroll
    for (int m = 0; m < 4; ++m)
        #pragma unroll
        for (int p = 0; p < 4; ++p) acc[m][p] = 0.0f;

    for (int chunk = 0; chunk < CIN / 32; ++chunk) {
        const int ic0 = chunk * 32;
        __syncthreads();
        // stage 3 rows x 128 interior pix x 32 ic, source-swizzled for bank-free reads
        #pragma unroll
        for (int it = 0; it < 6; ++it) {
            int u   = tid + 256 * it;
            int row = u >> 9;
            int rem = u & 511;
            int pix = rem >> 2;
            int s   = rem & 3;
            int icq = s ^ (((pix + 1) >> 1) & 3);
            const unsigned short* gp = in
                + ((size_t)((n130h + row) * 130 + pix + 1)) * CIN + ic0 + icq * 8;
            unsigned short* lp = (unsigned short*)((char*)lds + row * 8448 + 64 + rem * 16);
            GL_LDS(gp, lp);
        }
        __syncthreads();
        #pragma unroll
        for (int kk = 0; kk < 9; ++kk) {
            const int ky = kk / 3, kx = kk % 3;
            s16x8 af[4], bf[4];
            #pragma unroll
            for (int m = 0; m < 4; ++m)
                af[m] = *(const s16x8*)(wpk
                    + ((size_t)((chunk * 9 + kk) * (COUT / 16) + ocf0 + m)) * 512 + lane * 8);
            #pragma unroll
            for (int p = 0; p < 4; ++p)
                bf[p] = *(const s16x8*)((const char*)lds + ky * 8448 + addr12[p * 3 + kx]);
            #pragma unroll
            for (int m = 0; m < 4; ++m)
                #pragma unroll
                for (int p = 0; p < 4; ++p)
                    acc[m][p] = __builtin_amdgcn_mfma_f32_16x16x32_bf16(af[m], bf[p], acc[m][p], 0, 0, 0);
        }
    }

    // epilogue
    #pragma unroll
    for (int m = 0; m < 4; ++m) {
        const int oc4 = ocbase + m * 16 + g * 4;
        const f4v s4 = *(const f4v*)(sc + oc4);
        const f4v b4 = *(const f4v*)(bi + oc4);
        #pragma unroll
        for (int p = 0; p < 4; ++p) {
            const int pix = pixbase + p * 16 + c;
            float y[4];
            #pragma unroll
            for (int j = 0; j < 4; ++j) {
                y[j] = acc[m][p][j] * s4[j] + b4[j];
                if (RELU) y[j] = fmaxf(y[j], 0.0f);
            }
            if (OUTF32) {
                float* op = (float*)outv + (((size_t)n * COUT + oc4) << 14) + (h << 7) + pix;
                op[0] = y[0]; op[16384] = y[1]; op[32768] = y[2]; op[49152] = y[3];
            } else {
                u16x4 pk;
                #pragma unroll
                for (int j = 0; j < 4; ++j) pk[j] = f2bf(y[j]);
                // elem(n, h, pix, oc4) = ((n130h + 1)*130 + pix + 1)*COUT + oc4
                *(u16x4*)((unsigned short*)outv
                    + ((size_t)(n130h + 1) * 130 + pix + 1) * COUT + oc4) = pk;
            }
        }
    }
}

// ---------------------------------------------------------------------------
// conv1x1 + BN affine fused residual add + ReLU, in-place on io (bf16 NHWC pad).
// io = relu(io + (xb (*) w)*s + b).  grid (2, 128, 8)
// ---------------------------------------------------------------------------
__global__ __launch_bounds__(256, 2)
void conv1_mfma(const unsigned short* __restrict__ xb,
                const unsigned short* __restrict__ w1pk,
                const float* __restrict__ sc, const float* __restrict__ bi,
                unsigned short* __restrict__ io)
{
    const int tid  = threadIdx.x;
    const int h    = blockIdx.y;
    const int n    = blockIdx.z;
    const int lane = tid & 63;
    const int wv   = tid >> 6;
    const int c    = lane & 15;
    const int g    = lane >> 4;
    const int pixbase = (wv >> 1) * 64;
    const int ocbase  = blockIdx.x * 128 + (wv & 1) * 64;
    const int ocf0    = blockIdx.x * 8 + (wv & 1) * 4;
    const size_t pixrow = ((size_t)(n * 130 + h + 1) * 130 + (pixbase + c + 1)) * 256;

    f32x4 acc[4][4];
    #pragma unroll
    for (int m = 0; m < 4; ++m)
        #pragma unroll
        for (int p = 0; p < 4; ++p) acc[m][p] = 0.0f;

    s16x8 a0[4], b0[4], a1[4], b1[4];

#define LOADC(ck, A, B) do {                                                        \
    _Pragma("unroll") for (int p = 0; p < 4; ++p)                                   \
        B[p] = *(const s16x8*)(xb + pixrow + (size_t)(16 * p) * 256 + (ck) * 32 + g * 8); \
    _Pragma("unroll") for (int m = 0; m < 4; ++m)                                   \
        A[m] = *(const s16x8*)(w1pk + ((size_t)((ck) * 16 + ocf0 + m)) * 512 + lane * 8); \
} while (0)
#define MM(A, B)                                                                    \
    _Pragma("unroll") for (int m = 0; m < 4; ++m)                                   \
        _Pragma("unroll") for (int p = 0; p < 4; ++p)                               \
            acc[m][p] = __builtin_amdgcn_mfma_f32_16x16x32_bf16(A[m], B[p], acc[m][p], 0, 0, 0)

    LOADC(0, a0, b0);
    #pragma unroll
    for (int ck = 0; ck < 8; ++ck) {
        if ((ck & 1) == 0) { if (ck < 7) LOADC(ck + 1, a1, b1); MM(a0, b0); }
        else               { if (ck < 7) LOADC(ck + 1, a0, b0); MM(a1, b1); }
    }
#undef LOADC
#undef MM

    #pragma unroll
    for (int m = 0; m < 4; ++m) {
        const int oc4 = ocbase + m * 16 + g * 4;
        const f4v s4 = *(const f4v*)(sc + oc4);
        const f4v b4 = *(const f4v*)(bi + oc4);
        #pragma unroll
        for (int p = 0; p < 4; ++p) {
            const int pix = pixbase + p * 16 + c;
            size_t idx = ((size_t)(n * 130 + h + 1) * 130 + pix + 1) * 256 + oc4;
            u16x4 old = *(const u16x4*)(io + idx);
            u16x4 pk;
            #pragma unroll
            for (int j = 0; j < 4; ++j) {
                float y = acc[m][p][j] * s4[j] + b4[j] + bf2f(old[j]);
                pk[j] = f2bf(fmaxf(y, 0.0f));
            }
            *(u16x4*)(io + idx) = pk;
        }
    }
}

// ---------------------------------------------------------------------------
// in-place cummax along H (128-ch padded NHWC). grid 1024 = n*128 + w, block 128
// ---------------------------------------------------------------------------
template<bool REV>
__global__ __launch_bounds__(128)
void pool_h_k(unsigned short* __restrict__ p)
{
    const int n = blockIdx.x >> 7, w = blockIdx.x & 127, cth = threadIdx.x;
    unsigned short* base = p + (((size_t)n * 130 + 1) * 130 + (w + 1)) * 128 + cth;
    const int stride = 130 * 128;
    float m = -3.402823466e+38f;
    for (int i = 0; i < 128; ++i) {
        int hh = REV ? (127 - i) : i;
        unsigned short* q = base + (size_t)hh * stride;
        m = fmaxf(m, bf2f(*q));
        *q = f2bf(m);
    }
}

// ---------------------------------------------------------------------------
// tdst = cummaxW(lsrc) + tdst (both 128-ch padded NHWC). grid 1024 = n*128+h
// ---------------------------------------------------------------------------
template<bool REV>
__global__ __launch_bounds__(128)
void pool_w_add_k(const unsigned short* __restrict__ lsrc,
                  unsigned short* __restrict__ tdst)
{
    const int n = blockIdx.x >> 7, hh = blockIdx.x & 127, cth = threadIdx.x;
    const size_t rowbase = ((size_t)(n * 130 + hh + 1) * 130) * 128 + cth;
    float m = -3.402823466e+38f;
    for (int i = 0; i < 128; ++i) {
        int w = REV ? (127 - i) : i;
        size_t off = rowbase + (size_t)(w + 1) * 128;
        m = fmaxf(m, bf2f(lsrc[off]));
        tdst[off] = f2bf(m + bf2f(tdst[off]));
    }
}

// ---------------------------------------------------------------------------
// zero the pad ring of a padded NHWC tensor. grid (ceil(516*C/8/256), 8)
// ---------------------------------------------------------------------------
__global__ __launch_bounds__(256)
void padzero_k(unsigned short* __restrict__ t, int C)
{
    int idx = blockIdx.x * 256 + threadIdx.x;
    int n = blockIdx.y;
    int cpu = C >> 3;
    if (idx >= 516 * cpu) return;
    int cell = idx / cpu, cq = idx - cell * cpu;
    int h, w;
    if (cell < 260) { h = (cell < 130) ? -1 : 128; w = (cell % 130) - 1; }
    else { int j = cell - 260; w = (j < 128) ? -1 : 128; h = j & 127; }
    size_t off = (((size_t)n * 130 + h + 1) * 130 + (w + 1)) * C + cq * 8;
    uint4 z; z.x = 0; z.y = 0; z.z = 0; z.w = 0;
    *(uint4*)(t + off) = z;
}

// ---------------------------------------------------------------------------
// x fp32 NCHW -> bf16 NHWC padded interior. grid (128 h, 8 n), block 256
// ---------------------------------------------------------------------------
__global__ __launch_bounds__(256)
void transform_x_k(const float* __restrict__ x, unsigned short* __restrict__ xb)
{
    __shared__ float sm[64][132];
    const int h = blockIdx.x, n = blockIdx.y, t = threadIdx.x;
    for (int cc0 = 0; cc0 < 256; cc0 += 64) {
        __syncthreads();
        {
            int ci = t >> 7, wi = t & 127;
            #pragma unroll 8
            for (int k = 0; k < 32; ++k)
                sm[ci + 2 * k][wi] = x[((size_t)(n * 256 + cc0 + ci + 2 * k) << 14) + (h << 7) + wi];
        }
        __syncthreads();
        {
            int wi = t >> 1, cq = t & 1;
            unsigned short tmp[32];
            #pragma unroll
            for (int m2 = 0; m2 < 32; ++m2) tmp[m2] = f2bf(sm[cq * 32 + m2][wi]);
            unsigned short* dst = xb + (((size_t)n * 130 + h + 1) * 130 + wi + 1) * 256 + cc0 + cq * 32;
            #pragma unroll
            for (int q = 0; q < 4; ++q) *(uint4*)(dst + q * 8) = *(const uint4*)(tmp + q * 8);
        }
    }
}

// ---------------------------------------------------------------------------
// weight prepack conv3x3: OIHW fp32 -> frag-packed bf16
// frag = (chunk*9+kk)*(COUT/16) + oc>>4 ; lane = (icr>>3)*16 + (oc&15) ; j = icr&7
// ---------------------------------------------------------------------------
__global__ __launch_bounds__(256)
void prepack3_k(const float* __restrict__ w, unsigned short* __restrict__ dst,
                int CIN, int COUT)
{
    int idx = blockIdx.x * 256 + threadIdx.x;
    if (idx >= COUT * CIN * 9) return;
    int kk = idx % 9; int rest = idx / 9;
    int ic = rest % CIN; int oc = rest / CIN;
    float v = w[(size_t)(oc * CIN + ic) * 9 + kk];
    int chunk = ic >> 5, icr = ic & 31, gg = icr >> 3, j = icr & 7;
    int m = oc >> 4, ocr = oc & 15, ln = gg * 16 + ocr;
    size_t off = ((size_t)((chunk * 9 + kk) * (COUT / 16) + m)) * 512 + ln * 8 + j;
    dst[off] = f2bf(v);
}

__global__ __launch_bounds__(256)
void prepack1_k(const float* __restrict__ w, unsigned short* __restrict__ dst)
{
    int idx = blockIdx.x * 256 + threadIdx.x;   // 256*256
    if (idx >= 65536) return;
    int ic = idx & 255, oc = idx >> 8;
    float v = w[oc * 256 + ic];
    int chunk = ic >> 5, icr = ic & 31, gg = icr >> 3, j = icr & 7;
    int m = oc >> 4, ocr = oc & 15, ln = gg * 16 + ocr;
    size_t off = ((size_t)(chunk * 16 + m)) * 512 + ln * 8 + j;
    dst[off] = f2bf(v);
}

// ---------------------------------------------------------------------------
extern "C" void kernel_launch(void* const* d_in, const int* in_sizes, int n_in,
                              void* d_out, int out_size, void* d_ws, size_t ws_size,
                              hipStream_t stream)
{
    const float* x     = (const float*)d_in[0];
    const float* w_t   = (const float*)d_in[1];
    const float* s_t   = (const float*)d_in[2];
    const float* b_t   = (const float*)d_in[3];
    const float* w_l   = (const float*)d_in[4];
    const float* s_l   = (const float*)d_in[5];
    const float* b_l   = (const float*)d_in[6];
    const float* w_b   = (const float*)d_in[7];
    const float* s_b   = (const float*)d_in[8];
    const float* b_b   = (const float*)d_in[9];
    const float* w_r   = (const float*)d_in[10];
    const float* s_r   = (const float*)d_in[11];
    const float* b_r   = (const float*)d_in[12];
    const float* w_tl3 = (const float*)d_in[13];
    const float* s_tl3 = (const float*)d_in[14];
    const float* b_tl3 = (const float*)d_in[15];
    const float* w_br3 = (const float*)d_in[16];
    const float* s_br3 = (const float*)d_in[17];
    const float* b_br3 = (const float*)d_in[18];
    const float* w_tl1 = (const float*)d_in[19];
    const float* s_tl1 = (const float*)d_in[20];
    const float* b_tl1 = (const float*)d_in[21];
    const float* w_br1 = (const float*)d_in[22];
    const float* s_br1 = (const float*)d_in[23];
    const float* b_br1 = (const float*)d_in[24];
    const float* w_tlo = (const float*)d_in[25];
    const float* s_tlo = (const float*)d_in[26];
    const float* b_tlo = (const float*)d_in[27];
    const float* w_bro = (const float*)d_in[28];
    const float* s_bro = (const float*)d_in[29];
    const float* b_bro = (const float*)d_in[30];

    typedef unsigned short ush;
    const size_t T256 = (size_t)8 * 130 * 130 * 256;   // 34,611,200
    const size_t T128 = (size_t)8 * 130 * 130 * 128;   // 17,305,600

    ush* xb = (ush*)d_ws;
    ush* tt = xb + T256;
    ush* bb = tt + T128;
    ush* ll = bb + T128;
    ush* rr = ll + T128;
    ush* wq = rr + T128;
    ush* wp_t   = wq;
    ush* wp_l   = wp_t   + 294912;
    ush* wp_b   = wp_l   + 294912;
    ush* wp_r   = wp_b   + 294912;
    ush* wp_tl3 = wp_r   + 294912;
    ush* wp_br3 = wp_tl3 + 294912;
    ush* wp_tlo = wp_br3 + 294912;
    ush* wp_bro = wp_tlo + 589824;
    ush* wp_tl1 = wp_bro + 589824;
    ush* wp_br1 = wp_tl1 + 65536;
    ush* tl = ll;                                      // 256-ch buffer over l+r

    // weight prepacks
    prepack3_k<<<dim3((294912 + 255) / 256), dim3(256), 0, stream>>>(w_t,   wp_t,   256, 128);
    prepack3_k<<<dim3((294912 + 255) / 256), dim3(256), 0, stream>>>(w_l,   wp_l,   256, 128);
    prepack3_k<<<dim3((294912 + 255) / 256), dim3(256), 0, stream>>>(w_b,   wp_b,   256, 128);
    prepack3_k<<<dim3((294912 + 255) / 256), dim3(256), 0, stream>>>(w_r,   wp_r,   256, 128);
    prepack3_k<<<dim3((294912 + 255) / 256), dim3(256), 0, stream>>>(w_tl3, wp_tl3, 128, 256);
    prepack3_k<<<dim3((294912 + 255) / 256), dim3(256), 0, stream>>>(w_br3, wp_br3, 128, 256);
    prepack3_k<<<dim3((589824 + 255) / 256), dim3(256), 0, stream>>>(w_tlo, wp_tlo, 256, 256);
    prepack3_k<<<dim3((589824 + 255) / 256), dim3(256), 0, stream>>>(w_bro, wp_bro, 256, 256);
    prepack1_k<<<dim3(256), dim3(256), 0, stream>>>(w_tl1, wp_tl1);
    prepack1_k<<<dim3(256), dim3(256), 0, stream>>>(w_br1, wp_br1);

    // pad rings
    padzero_k<<<dim3(66, 8), dim3(256), 0, stream>>>(xb, 256);
    padzero_k<<<dim3(33, 8), dim3(256), 0, stream>>>(tt, 128);
    padzero_k<<<dim3(33, 8), dim3(256), 0, stream>>>(bb, 128);
    padzero_k<<<dim3(33, 8), dim3(256), 0, stream>>>(ll, 128);
    padzero_k<<<dim3(33, 8), dim3(256), 0, stream>>>(rr, 128);

    // x -> bf16 NHWC padded
    transform_x_k<<<dim3(128, 8), dim3(256), 0, stream>>>(x, xb);

    // stage A: four conv3x3 (Cin=256 -> 128, relu)
    conv3_mfma<256, 128, true, false><<<dim3(1, 128, 8), dim3(256), 0, stream>>>(xb, wp_t, s_t, b_t, tt);
    conv3_mfma<256, 128, true, false><<<dim3(1, 128, 8), dim3(256), 0, stream>>>(xb, wp_l, s_l, b_l, ll);
    conv3_mfma<256, 128, true, false><<<dim3(1, 128, 8), dim3(256), 0, stream>>>(xb, wp_b, s_b, b_b, bb);
    conv3_mfma<256, 128, true, false><<<dim3(1, 128, 8), dim3(256), 0, stream>>>(xb, wp_r, s_r, b_r, rr);

    // pools: tt = u1 = revcummaxH(t)+revcummaxW(l); bb = u2 = cummaxH(b)+cummaxW(r)
    pool_h_k<true ><<<dim3(1024), dim3(128), 0, stream>>>(tt);
    pool_h_k<false><<<dim3(1024), dim3(128), 0, stream>>>(bb);
    pool_w_add_k<true ><<<dim3(1024), dim3(128), 0, stream>>>(ll, tt);
    pool_w_add_k<false><<<dim3(1024), dim3(128), 0, stream>>>(rr, bb);

    // tl chain (tl buffer overlays ll+rr, now dead)
    padzero_k<<<dim3(66, 8), dim3(256), 0, stream>>>(tl, 256);
    conv3_mfma<128, 256, false, false><<<dim3(2, 128, 8), dim3(256), 0, stream>>>(tt, wp_tl3, s_tl3, b_tl3, tl);
    conv1_mfma<<<dim3(2, 128, 8), dim3(256), 0, stream>>>(xb, wp_tl1, s_tl1, b_tl1, tl);
    conv3_mfma<256, 256, true, true><<<dim3(2, 128, 8), dim3(256), 0, stream>>>(tl, wp_tlo, s_tlo, b_tlo, d_out);

    // br chain (reuses tl buffer; pads still zero)
    conv3_mfma<128, 256, false, false><<<dim3(2, 128, 8), dim3(256), 0, stream>>>(bb, wp_br3, s_br3, b_br3, tl);
    conv1_mfma<<<dim3(2, 128, 8), dim3(256), 0, stream>>>(xb, wp_br1, s_br1, b_br1, tl);
    conv3_mfma<256, 256, true, true><<<dim3(2, 128, 8), dim3(256), 0, stream>>>(tl, wp_bro, s_bro, b_bro,
                                                                                (float*)d_out + 33554432);
}

// Round 4
// 1298.838 us; speedup vs baseline: 13.6899x; 1.5726x over previous
//
#include <hip/hip_runtime.h>
#include <cstdint>
#include <cstddef>

// B=8, C=256/128, H=W=128. Padded NHWC bf16 tensors: [n][130][130][C], pad ring = 0.
// elem(n,h,w,c) = ((n*130 + h+1)*130 + (w+1))*C + c

typedef float  f32x4 __attribute__((ext_vector_type(4)));
typedef float  f4v   __attribute__((ext_vector_type(4)));
typedef short  s16x8 __attribute__((ext_vector_type(8)));
typedef unsigned short u16x4 __attribute__((ext_vector_type(4)));

__device__ __forceinline__ float bf2f(unsigned short u) {
    unsigned x = ((unsigned)u) << 16;
    return __builtin_bit_cast(float, x);
}
__device__ __forceinline__ unsigned short f2bf(float f) {
    unsigned u = __builtin_bit_cast(unsigned, f);
    unsigned r = (u + 0x7fffu + ((u >> 16) & 1u)) >> 16;
    return (unsigned short)r;
}

#define GL_LDS(gp, lp) __builtin_amdgcn_global_load_lds( \
    (const __attribute__((address_space(1))) unsigned int*)(const void*)(gp), \
    (__attribute__((address_space(3))) unsigned int*)(void*)(lp), 16, 0, 0)

// ---------------------------------------------------------------------------
// conv3x3 + BN affine (+opt ReLU), bf16 MFMA implicit GEMM.
// block 256 thr = 4 waves; tile = 128 oc x 128 pix (one image row); K = CIN*9.
// 2-phase pipeline: double-buffered LDS, stage(c+1) issued before compute(c),
// ONE __syncthreads per chunk (its vmcnt(0) drain lands after the MFMA phase).
// grid (COUT/128, 128 h, 8 n)
// ---------------------------------------------------------------------------
template<int CIN, int COUT, bool RELU, bool OUTF32>
__global__ __launch_bounds__(256, 3)
void conv3_mfma(const unsigned short* __restrict__ in,
                const unsigned short* __restrict__ wpk,
                const float* __restrict__ sc, const float* __restrict__ bi,
                void* __restrict__ outv)
{
    __shared__ unsigned short lds[2][3 * 4224]; // 2 x [3 rows][132 ps][32 ic], row stride 8448 B
    const int tid  = threadIdx.x;
    const int h    = blockIdx.y;
    const int n    = blockIdx.z;
    const int lane = tid & 63;
    const int wv   = tid >> 6;
    const int c    = lane & 15;
    const int g    = lane >> 4;
    const int pixbase = (wv >> 1) * 64;
    const int ocbase  = blockIdx.x * 128 + (wv & 1) * 64;
    const int ocf0    = blockIdx.x * 8 + (wv & 1) * 4;   // first oc-frag index (global)
    const int n130h   = n * 130 + h;

    // B-frag LDS byte addresses [p][kx] (ky term added as compile-time offset)
    int addr12[12];
    #pragma unroll
    for (int p = 0; p < 4; ++p)
        #pragma unroll
        for (int kx = 0; kx < 3; ++kx) {
            int ps = pixbase + 16 * p + c + kx;           // padded col index
            addr12[p * 3 + kx] = ps * 64 + ((g ^ ((ps >> 1) & 3)) << 4);
        }

    // halo columns ps=0 and ps=129 are always zero (image border) - write once, both buffers
    if (tid < 48) {
        int bsel = tid >= 24;
        int v  = tid - bsel * 24;
        int rr = v >> 3, side = (v >> 2) & 1, q = v & 3;
        int ps = side ? 129 : 0;
        uint4 z; z.x = 0; z.y = 0; z.z = 0; z.w = 0;
        *(uint4*)((char*)&lds[bsel][0] + rr * 8448 + ps * 64 + q * 16) = z;
    }

    // stage one 32-ic chunk (3 rows x 128 interior pix), source-swizzled
    auto STAGE = [&](int chunk, int bsel) {
        const int ic0 = chunk * 32;
        #pragma unroll
        for (int it = 0; it < 6; ++it) {
            int u   = tid + 256 * it;
            int row = u >> 9;
            int rem = u & 511;
            int pix = rem >> 2;
            int s   = rem & 3;
            int icq = s ^ (((pix + 1) >> 1) & 3);
            const unsigned short* gp = in
                + ((size_t)((n130h + row) * 130 + pix + 1)) * CIN + ic0 + icq * 8;
            unsigned short* lp = (unsigned short*)((char*)&lds[bsel][0] + row * 8448 + 64 + rem * 16);
            GL_LDS(gp, lp);
        }
    };

    f32x4 acc[4][4];
    #pragma unroll
    for (int m = 0; m < 4; ++m)
        #pragma unroll
        for (int p = 0; p < 4; ++p) acc[m][p] = 0.0f;

    const int NC = CIN / 32;
    STAGE(0, 0);
    __syncthreads();

    for (int chunk = 0; chunk < NC; ++chunk) {
        const int cur = chunk & 1;
        if (chunk + 1 < NC) STAGE(chunk + 1, cur ^ 1);   // prefetch next (overlaps MFMA below)
        const char* lb = (const char*)&lds[cur][0];
        #pragma unroll
        for (int kk = 0; kk < 9; ++kk) {
            const int ky = kk / 3, kx = kk % 3;
            s16x8 af[4], bf[4];
            #pragma unroll
            for (int m = 0; m < 4; ++m)
                af[m] = *(const s16x8*)(wpk
                    + ((size_t)((chunk * 9 + kk) * (COUT / 16) + ocf0 + m)) * 512 + lane * 8);
            #pragma unroll
            for (int p = 0; p < 4; ++p)
                bf[p] = *(const s16x8*)(lb + ky * 8448 + addr12[p * 3 + kx]);
            #pragma unroll
            for (int m = 0; m < 4; ++m)
                #pragma unroll
                for (int p = 0; p < 4; ++p)
                    acc[m][p] = __builtin_amdgcn_mfma_f32_16x16x32_bf16(af[m], bf[p], acc[m][p], 0, 0, 0);
        }
        __syncthreads();   // drains this wave's prefetch loads (after compute) + LDS reads
    }

    // epilogue
    #pragma unroll
    for (int m = 0; m < 4; ++m) {
        const int oc4 = ocbase + m * 16 + g * 4;
        const f4v s4 = *(const f4v*)(sc + oc4);
        const f4v b4 = *(const f4v*)(bi + oc4);
        #pragma unroll
        for (int p = 0; p < 4; ++p) {
            const int pix = pixbase + p * 16 + c;
            float y[4];
            #pragma unroll
            for (int j = 0; j < 4; ++j) {
                y[j] = acc[m][p][j] * s4[j] + b4[j];
                if (RELU) y[j] = fmaxf(y[j], 0.0f);
            }
            if (OUTF32) {
                float* op = (float*)outv + (((size_t)n * COUT + oc4) << 14) + (h << 7) + pix;
                op[0] = y[0]; op[16384] = y[1]; op[32768] = y[2]; op[49152] = y[3];
            } else {
                u16x4 pk;
                #pragma unroll
                for (int j = 0; j < 4; ++j) pk[j] = f2bf(y[j]);
                // elem(n, h, pix, oc4) = ((n130h + 1)*130 + pix + 1)*COUT + oc4
                *(u16x4*)((unsigned short*)outv
                    + ((size_t)(n130h + 1) * 130 + pix + 1) * COUT + oc4) = pk;
            }
        }
    }
}

// ---------------------------------------------------------------------------
// conv1x1 + BN affine fused residual add + ReLU, in-place on io (bf16 NHWC pad).
// io = relu(io + (xb (*) w)*s + b).  grid (2, 128, 8)
// ---------------------------------------------------------------------------
__global__ __launch_bounds__(256, 2)
void conv1_mfma(const unsigned short* __restrict__ xb,
                const unsigned short* __restrict__ w1pk,
                const float* __restrict__ sc, const float* __restrict__ bi,
                unsigned short* __restrict__ io)
{
    const int tid  = threadIdx.x;
    const int h    = blockIdx.y;
    const int n    = blockIdx.z;
    const int lane = tid & 63;
    const int wv   = tid >> 6;
    const int c    = lane & 15;
    const int g    = lane >> 4;
    const int pixbase = (wv >> 1) * 64;
    const int ocbase  = blockIdx.x * 128 + (wv & 1) * 64;
    const int ocf0    = blockIdx.x * 8 + (wv & 1) * 4;
    const size_t pixrow = ((size_t)(n * 130 + h + 1) * 130 + (pixbase + c + 1)) * 256;

    f32x4 acc[4][4];
    #pragma unroll
    for (int m = 0; m < 4; ++m)
        #pragma unroll
        for (int p = 0; p < 4; ++p) acc[m][p] = 0.0f;

    s16x8 a0[4], b0[4], a1[4], b1[4];

#define LOADC(ck, A, B) do {                                                        \
    _Pragma("unroll") for (int p = 0; p < 4; ++p)                                   \
        B[p] = *(const s16x8*)(xb + pixrow + (size_t)(16 * p) * 256 + (ck) * 32 + g * 8); \
    _Pragma("unroll") for (int m = 0; m < 4; ++m)                                   \
        A[m] = *(const s16x8*)(w1pk + ((size_t)((ck) * 16 + ocf0 + m)) * 512 + lane * 8); \
} while (0)
#define MM(A, B)                                                                    \
    _Pragma("unroll") for (int m = 0; m < 4; ++m)                                   \
        _Pragma("unroll") for (int p = 0; p < 4; ++p)                               \
            acc[m][p] = __builtin_amdgcn_mfma_f32_16x16x32_bf16(A[m], B[p], acc[m][p], 0, 0, 0)

    LOADC(0, a0, b0);
    #pragma unroll
    for (int ck = 0; ck < 8; ++ck) {
        if ((ck & 1) == 0) { if (ck < 7) LOADC(ck + 1, a1, b1); MM(a0, b0); }
        else               { if (ck < 7) LOADC(ck + 1, a0, b0); MM(a1, b1); }
    }
#undef LOADC
#undef MM

    #pragma unroll
    for (int m = 0; m < 4; ++m) {
        const int oc4 = ocbase + m * 16 + g * 4;
        const f4v s4 = *(const f4v*)(sc + oc4);
        const f4v b4 = *(const f4v*)(bi + oc4);
        #pragma unroll
        for (int p = 0; p < 4; ++p) {
            const int pix = pixbase + p * 16 + c;
            size_t idx = ((size_t)(n * 130 + h + 1) * 130 + pix + 1) * 256 + oc4;
            u16x4 old = *(const u16x4*)(io + idx);
            u16x4 pk;
            #pragma unroll
            for (int j = 0; j < 4; ++j) {
                float y = acc[m][p][j] * s4[j] + b4[j] + bf2f(old[j]);
                pk[j] = f2bf(fmaxf(y, 0.0f));
            }
            *(u16x4*)(io + idx) = pk;
        }
    }
}

// ---------------------------------------------------------------------------
// in-place cummax along H (128-ch padded NHWC). grid 1024 = n*128 + w, block 128
// ---------------------------------------------------------------------------
template<bool REV>
__global__ __launch_bounds__(128)
void pool_h_k(unsigned short* __restrict__ p)
{
    const int n = blockIdx.x >> 7, w = blockIdx.x & 127, cth = threadIdx.x;
    unsigned short* base = p + (((size_t)n * 130 + 1) * 130 + (w + 1)) * 128 + cth;
    const int stride = 130 * 128;
    float m = -3.402823466e+38f;
    for (int i = 0; i < 128; ++i) {
        int hh = REV ? (127 - i) : i;
        unsigned short* q = base + (size_t)hh * stride;
        m = fmaxf(m, bf2f(*q));
        *q = f2bf(m);
    }
}

// ---------------------------------------------------------------------------
// tdst = cummaxW(lsrc) + tdst (both 128-ch padded NHWC). grid 1024 = n*128+h
// ---------------------------------------------------------------------------
template<bool REV>
__global__ __launch_bounds__(128)
void pool_w_add_k(const unsigned short* __restrict__ lsrc,
                  unsigned short* __restrict__ tdst)
{
    const int n = blockIdx.x >> 7, hh = blockIdx.x & 127, cth = threadIdx.x;
    const size_t rowbase = ((size_t)(n * 130 + hh + 1) * 130) * 128 + cth;
    float m = -3.402823466e+38f;
    for (int i = 0; i < 128; ++i) {
        int w = REV ? (127 - i) : i;
        size_t off = rowbase + (size_t)(w + 1) * 128;
        m = fmaxf(m, bf2f(lsrc[off]));
        tdst[off] = f2bf(m + bf2f(tdst[off]));
    }
}

// ---------------------------------------------------------------------------
// zero the pad ring of a padded NHWC tensor. grid (ceil(516*C/8/256), 8)
// ---------------------------------------------------------------------------
__global__ __launch_bounds__(256)
void padzero_k(unsigned short* __restrict__ t, int C)
{
    int idx = blockIdx.x * 256 + threadIdx.x;
    int n = blockIdx.y;
    int cpu = C >> 3;
    if (idx >= 516 * cpu) return;
    int cell = idx / cpu, cq = idx - cell * cpu;
    int h, w;
    if (cell < 260) { h = (cell < 130) ? -1 : 128; w = (cell % 130) - 1; }
    else { int j = cell - 260; w = (j < 128) ? -1 : 128; h = j & 127; }
    size_t off = (((size_t)n * 130 + h + 1) * 130 + (w + 1)) * C + cq * 8;
    uint4 z; z.x = 0; z.y = 0; z.z = 0; z.w = 0;
    *(uint4*)(t + off) = z;
}

// ---------------------------------------------------------------------------
// x fp32 NCHW -> bf16 NHWC padded interior. grid (128 h, 8 n), block 256
// ---------------------------------------------------------------------------
__global__ __launch_bounds__(256)
void transform_x_k(const float* __restrict__ x, unsigned short* __restrict__ xb)
{
    __shared__ float sm[64][132];
    const int h = blockIdx.x, n = blockIdx.y, t = threadIdx.x;
    for (int cc0 = 0; cc0 < 256; cc0 += 64) {
        __syncthreads();
        {
            int ci = t >> 7, wi = t & 127;
            #pragma unroll 8
            for (int k = 0; k < 32; ++k)
                sm[ci + 2 * k][wi] = x[((size_t)(n * 256 + cc0 + ci + 2 * k) << 14) + (h << 7) + wi];
        }
        __syncthreads();
        {
            int wi = t >> 1, cq = t & 1;
            unsigned short tmp[32];
            #pragma unroll
            for (int m2 = 0; m2 < 32; ++m2) tmp[m2] = f2bf(sm[cq * 32 + m2][wi]);
            unsigned short* dst = xb + (((size_t)n * 130 + h + 1) * 130 + wi + 1) * 256 + cc0 + cq * 32;
            #pragma unroll
            for (int q = 0; q < 4; ++q) *(uint4*)(dst + q * 8) = *(const uint4*)(tmp + q * 8);
        }
    }
}

// ---------------------------------------------------------------------------
// weight prepack conv3x3: OIHW fp32 -> frag-packed bf16
// frag = (chunk*9+kk)*(COUT/16) + oc>>4 ; lane = (icr>>3)*16 + (oc&15) ; j = icr&7
// ---------------------------------------------------------------------------
__global__ __launch_bounds__(256)
void prepack3_k(const float* __restrict__ w, unsigned short* __restrict__ dst,
                int CIN, int COUT)
{
    int idx = blockIdx.x * 256 + threadIdx.x;
    if (idx >= COUT * CIN * 9) return;
    int kk = idx % 9; int rest = idx / 9;
    int ic = rest % CIN; int oc = rest / CIN;
    float v = w[(size_t)(oc * CIN + ic) * 9 + kk];
    int chunk = ic >> 5, icr = ic & 31, gg = icr >> 3, j = icr & 7;
    int m = oc >> 4, ocr = oc & 15, ln = gg * 16 + ocr;
    size_t off = ((size_t)((chunk * 9 + kk) * (COUT / 16) + m)) * 512 + ln * 8 + j;
    dst[off] = f2bf(v);
}

__global__ __launch_bounds__(256)
void prepack1_k(const float* __restrict__ w, unsigned short* __restrict__ dst)
{
    int idx = blockIdx.x * 256 + threadIdx.x;   // 256*256
    if (idx >= 65536) return;
    int ic = idx & 255, oc = idx >> 8;
    float v = w[oc * 256 + ic];
    int chunk = ic >> 5, icr = ic & 31, gg = icr >> 3, j = icr & 7;
    int m = oc >> 4, ocr = oc & 15, ln = gg * 16 + ocr;
    size_t off = ((size_t)(chunk * 16 + m)) * 512 + ln * 8 + j;
    dst[off] = f2bf(v);
}

// ---------------------------------------------------------------------------
extern "C" void kernel_launch(void* const* d_in, const int* in_sizes, int n_in,
                              void* d_out, int out_size, void* d_ws, size_t ws_size,
                              hipStream_t stream)
{
    const float* x     = (const float*)d_in[0];
    const float* w_t   = (const float*)d_in[1];
    const float* s_t   = (const float*)d_in[2];
    const float* b_t   = (const float*)d_in[3];
    const float* w_l   = (const float*)d_in[4];
    const float* s_l   = (const float*)d_in[5];
    const float* b_l   = (const float*)d_in[6];
    const float* w_b   = (const float*)d_in[7];
    const float* s_b   = (const float*)d_in[8];
    const float* b_b   = (const float*)d_in[9];
    const float* w_r   = (const float*)d_in[10];
    const float* s_r   = (const float*)d_in[11];
    const float* b_r   = (const float*)d_in[12];
    const float* w_tl3 = (const float*)d_in[13];
    const float* s_tl3 = (const float*)d_in[14];
    const float* b_tl3 = (const float*)d_in[15];
    const float* w_br3 = (const float*)d_in[16];
    const float* s_br3 = (const float*)d_in[17];
    const float* b_br3 = (const float*)d_in[18];
    const float* w_tl1 = (const float*)d_in[19];
    const float* s_tl1 = (const float*)d_in[20];
    const float* b_tl1 = (const float*)d_in[21];
    const float* w_br1 = (const float*)d_in[22];
    const float* s_br1 = (const float*)d_in[23];
    const float* b_br1 = (const float*)d_in[24];
    const float* w_tlo = (const float*)d_in[25];
    const float* s_tlo = (const float*)d_in[26];
    const float* b_tlo = (const float*)d_in[27];
    const float* w_bro = (const float*)d_in[28];
    const float* s_bro = (const float*)d_in[29];
    const float* b_bro = (const float*)d_in[30];

    typedef unsigned short ush;
    const size_t T256 = (size_t)8 * 130 * 130 * 256;   // 34,611,200
    const size_t T128 = (size_t)8 * 130 * 130 * 128;   // 17,305,600

    ush* xb = (ush*)d_ws;
    ush* tt = xb + T256;
    ush* bb = tt + T128;
    ush* ll = bb + T128;
    ush* rr = ll + T128;
    ush* wq = rr + T128;
    ush* wp_t   = wq;
    ush* wp_l   = wp_t   + 294912;
    ush* wp_b   = wp_l   + 294912;
    ush* wp_r   = wp_b   + 294912;
    ush* wp_tl3 = wp_r   + 294912;
    ush* wp_br3 = wp_tl3 + 294912;
    ush* wp_tlo = wp_br3 + 294912;
    ush* wp_bro = wp_tlo + 589824;
    ush* wp_tl1 = wp_bro + 589824;
    ush* wp_br1 = wp_tl1 + 65536;
    ush* tl = ll;                                      // 256-ch buffer over l+r

    // weight prepacks
    prepack3_k<<<dim3((294912 + 255) / 256), dim3(256), 0, stream>>>(w_t,   wp_t,   256, 128);
    prepack3_k<<<dim3((294912 + 255) / 256), dim3(256), 0, stream>>>(w_l,   wp_l,   256, 128);
    prepack3_k<<<dim3((294912 + 255) / 256), dim3(256), 0, stream>>>(w_b,   wp_b,   256, 128);
    prepack3_k<<<dim3((294912 + 255) / 256), dim3(256), 0, stream>>>(w_r,   wp_r,   256, 128);
    prepack3_k<<<dim3((294912 + 255) / 256), dim3(256), 0, stream>>>(w_tl3, wp_tl3, 128, 256);
    prepack3_k<<<dim3((294912 + 255) / 256), dim3(256), 0, stream>>>(w_br3, wp_br3, 128, 256);
    prepack3_k<<<dim3((589824 + 255) / 256), dim3(256), 0, stream>>>(w_tlo, wp_tlo, 256, 256);
    prepack3_k<<<dim3((589824 + 255) / 256), dim3(256), 0, stream>>>(w_bro, wp_bro, 256, 256);
    prepack1_k<<<dim3(256), dim3(256), 0, stream>>>(w_tl1, wp_tl1);
    prepack1_k<<<dim3(256), dim3(256), 0, stream>>>(w_br1, wp_br1);

    // pad rings
    padzero_k<<<dim3(66, 8), dim3(256), 0, stream>>>(xb, 256);
    padzero_k<<<dim3(33, 8), dim3(256), 0, stream>>>(tt, 128);
    padzero_k<<<dim3(33, 8), dim3(256), 0, stream>>>(bb, 128);
    padzero_k<<<dim3(33, 8), dim3(256), 0, stream>>>(ll, 128);
    padzero_k<<<dim3(33, 8), dim3(256), 0, stream>>>(rr, 128);

    // x -> bf16 NHWC padded
    transform_x_k<<<dim3(128, 8), dim3(256), 0, stream>>>(x, xb);

    // stage A: four conv3x3 (Cin=256 -> 128, relu)
    conv3_mfma<256, 128, true, false><<<dim3(1, 128, 8), dim3(256), 0, stream>>>(xb, wp_t, s_t, b_t, tt);
    conv3_mfma<256, 128, true, false><<<dim3(1, 128, 8), dim3(256), 0, stream>>>(xb, wp_l, s_l, b_l, ll);
    conv3_mfma<256, 128, true, false><<<dim3(1, 128, 8), dim3(256), 0, stream>>>(xb, wp_b, s_b, b_b, bb);
    conv3_mfma<256, 128, true, false><<<dim3(1, 128, 8), dim3(256), 0, stream>>>(xb, wp_r, s_r, b_r, rr);

    // pools: tt = u1 = revcummaxH(t)+revcummaxW(l); bb = u2 = cummaxH(b)+cummaxW(r)
    pool_h_k<true ><<<dim3(1024), dim3(128), 0, stream>>>(tt);
    pool_h_k<false><<<dim3(1024), dim3(128), 0, stream>>>(bb);
    pool_w_add_k<true ><<<dim3(1024), dim3(128), 0, stream>>>(ll, tt);
    pool_w_add_k<false><<<dim3(1024), dim3(128), 0, stream>>>(rr, bb);

    // tl chain (tl buffer overlays ll+rr, now dead)
    padzero_k<<<dim3(66, 8), dim3(256), 0, stream>>>(tl, 256);
    conv3_mfma<128, 256, false, false><<<dim3(2, 128, 8), dim3(256), 0, stream>>>(tt, wp_tl3, s_tl3, b_tl3, tl);
    conv1_mfma<<<dim3(2, 128, 8), dim3(256), 0, stream>>>(xb, wp_tl1, s_tl1, b_tl1, tl);
    conv3_mfma<256, 256, true, true><<<dim3(2, 128, 8), dim3(256), 0, stream>>>(tl, wp_tlo, s_tlo, b_tlo, d_out);

    // br chain (reuses tl buffer; pads still zero)
    conv3_mfma<128, 256, false, false><<<dim3(2, 128, 8), dim3(256), 0, stream>>>(bb, wp_br3, s_br3, b_br3, tl);
    conv1_mfma<<<dim3(2, 128, 8), dim3(256), 0, stream>>>(xb, wp_br1, s_br1, b_br1, tl);
    conv3_mfma<256, 256, true, true><<<dim3(2, 128, 8), dim3(256), 0, stream>>>(tl, wp_bro, s_bro, b_bro,
                                                                                (float*)d_out + 33554432);
}

// Round 5
// 1046.005 us; speedup vs baseline: 16.9989x; 1.2417x over previous
//
#include <hip/hip_runtime.h>
#include <cstdint>
#include <cstddef>

// B=8, C=256/128, H=W=128. Padded NHWC bf16 tensors: [n][130][130][C], pad ring = 0.
// elem(n,h,w,c) = ((n*130 + h+1)*130 + (w+1))*C + c

typedef float  f32x4 __attribute__((ext_vector_type(4)));
typedef float  f4v   __attribute__((ext_vector_type(4)));
typedef short  s16x8 __attribute__((ext_vector_type(8)));
typedef unsigned short u16x4 __attribute__((ext_vector_type(4)));

__device__ __forceinline__ float bf2f(unsigned short u) {
    unsigned x = ((unsigned)u) << 16;
    return __builtin_bit_cast(float, x);
}
__device__ __forceinline__ unsigned short f2bf(float f) {
    unsigned u = __builtin_bit_cast(unsigned, f);
    unsigned r = (u + 0x7fffu + ((u >> 16) & 1u)) >> 16;
    return (unsigned short)r;
}

#define GL_LDS(gp, lp) __builtin_amdgcn_global_load_lds( \
    (const __attribute__((address_space(1))) unsigned int*)(const void*)(gp), \
    (__attribute__((address_space(3))) unsigned int*)(void*)(lp), 16, 0, 0)

// ---------------------------------------------------------------------------
// conv3x3 + BN affine (+opt ReLU), bf16 MFMA implicit GEMM.
// block 256 thr = 4 waves. Output tile: 2 rows x 64 cols x 128 oc.
//   wave wv: row r = wv>>1, oc-half = wv&1. Per wave 64 px x 64 oc (acc 4x4).
// LDS buffer: 4 input rows x 66 cols x 32 ic (+512B slack) = 17408 B, x2 dbuf.
//   staging loads the padded tensor directly (pad ring supplies zeros).
// 2-phase pipeline: STAGE(c+1) before compute(c), one __syncthreads per chunk.
// grid ((COUT/128)*2 [octile*2+wtile], 64 h-pairs, 8 n)
// ---------------------------------------------------------------------------
template<int CIN, int COUT, bool RELU, bool OUTF32>
__global__ __launch_bounds__(256, 4)
void conv3_mfma(const unsigned short* __restrict__ in,
                const unsigned short* __restrict__ wpk,
                const float* __restrict__ sc, const float* __restrict__ bi,
                void* __restrict__ outv)
{
    __shared__ unsigned short lds[2][8704];      // 2 x 17408 B
    const int tid  = threadIdx.x;
    const int lane = tid & 63;
    const int wv   = tid >> 6;
    const int c    = lane & 15;
    const int g    = lane >> 4;
    const int gx     = blockIdx.x;
    const int wtile  = gx & 1;
    const int octile = gx >> 1;
    const int h0   = blockIdx.y * 2;
    const int n    = blockIdx.z;
    const int w0   = wtile * 64;
    const int r    = wv >> 1;                    // wave's output row (0/1)
    const int ocbase = octile * 128 + (wv & 1) * 64;
    const int ocf0   = octile * 8 + (wv & 1) * 4;

    // B-read base addrs: ps = 16p + c + kx; XOR term is p-independent
    // (16p >> 1 = 8p, 8p & 3 = 0), so only kx varies: 3 regs, p/ky via imm.
    int addrB[3];
    #pragma unroll
    for (int kx = 0; kx < 3; ++kx) {
        int ps0 = c + kx;
        addrB[kx] = r * 4224 + ps0 * 64 + ((g ^ ((ps0 >> 1) & 3)) << 4);
    }

    // staging source offsets (chunk-invariant, elements): unit u = it*256 + tid,
    // row = u/264, ps = (u%264)>>2, s = u&3, icq = s ^ swz(ps).
    // it=4 (issued by wave 0 only) stages units 1024..1087: tail of row 3 +
    // 32 garbage units into LDS slack (reads stay inside d_ws).
    int so[5];
    #pragma unroll
    for (int it = 0; it < 5; ++it) {
        int u   = it * 256 + tid;
        int row = u / 264;
        int rem = u - row * 264;
        int ps  = rem >> 2;
        int s   = rem & 3;
        int icq = s ^ ((ps >> 1) & 3);
        so[it] = ((n * 130 + h0 + row) * 130 + (w0 + ps)) * CIN + icq * 8;
    }

    auto STAGE = [&](int chunk, int bsel) {
        const unsigned short* bp = in + chunk * 32;
        char* lb = (char*)lds + bsel * 17408 + tid * 16;
        #pragma unroll
        for (int it = 0; it < 4; ++it)
            GL_LDS(bp + so[it], lb + it * 4096);
        if (wv == 0)
            GL_LDS(bp + so[4], lb + 16384);
    };

    f32x4 acc[4][4];
    #pragma unroll
    for (int m = 0; m < 4; ++m)
        #pragma unroll
        for (int p = 0; p < 4; ++p) acc[m][p] = 0.0f;

    const int NC = CIN / 32;
    STAGE(0, 0);
    __syncthreads();

    for (int chunk = 0; chunk < NC; ++chunk) {
        const int cur = chunk & 1;
        if (chunk + 1 < NC) STAGE(chunk + 1, cur ^ 1);  // prefetch overlaps MFMA
        const char* lb = (const char*)lds + cur * 17408;
        #pragma unroll
        for (int kk = 0; kk < 9; ++kk) {
            const int ky = kk / 3, kx = kk % 3;
            s16x8 af[4], bf[4];
            #pragma unroll
            for (int m = 0; m < 4; ++m)
                af[m] = *(const s16x8*)(wpk
                    + ((size_t)((chunk * 9 + kk) * (COUT / 16) + ocf0 + m)) * 512 + lane * 8);
            #pragma unroll
            for (int p = 0; p < 4; ++p)
                bf[p] = *(const s16x8*)(lb + addrB[kx] + ky * 4224 + p * 1024);
            #pragma unroll
            for (int m = 0; m < 4; ++m)
                #pragma unroll
                for (int p = 0; p < 4; ++p)
                    acc[m][p] = __builtin_amdgcn_mfma_f32_16x16x32_bf16(af[m], bf[p], acc[m][p], 0, 0, 0);
        }
        __syncthreads();   // drains this wave's prefetch + LDS reads, after compute
    }

    // epilogue: wave (r, ochalf) writes row h0+r, cols w0..w0+63
    #pragma unroll
    for (int m = 0; m < 4; ++m) {
        const int oc4 = ocbase + m * 16 + g * 4;
        const f4v s4 = *(const f4v*)(sc + oc4);
        const f4v b4 = *(const f4v*)(bi + oc4);
        #pragma unroll
        for (int p = 0; p < 4; ++p) {
            const int w = w0 + p * 16 + c;
            float y[4];
            #pragma unroll
            for (int j = 0; j < 4; ++j) {
                y[j] = acc[m][p][j] * s4[j] + b4[j];
                if (RELU) y[j] = fmaxf(y[j], 0.0f);
            }
            if (OUTF32) {
                float* op = (float*)outv + (((size_t)n * COUT + oc4) << 14) + ((h0 + r) << 7) + w;
                op[0] = y[0]; op[16384] = y[1]; op[32768] = y[2]; op[49152] = y[3];
            } else {
                u16x4 pk;
                #pragma unroll
                for (int j = 0; j < 4; ++j) pk[j] = f2bf(y[j]);
                *(u16x4*)((unsigned short*)outv
                    + ((size_t)(n * 130 + h0 + r + 1) * 130 + w + 1) * COUT + oc4) = pk;
            }
        }
    }
}

// ---------------------------------------------------------------------------
// conv1x1 + BN affine fused residual add + ReLU, in-place on io (bf16 NHWC pad).
// io = relu(io + (xb (*) w)*s + b).  grid (2, 128, 8)
// ---------------------------------------------------------------------------
__global__ __launch_bounds__(256, 2)
void conv1_mfma(const unsigned short* __restrict__ xb,
                const unsigned short* __restrict__ w1pk,
                const float* __restrict__ sc, const float* __restrict__ bi,
                unsigned short* __restrict__ io)
{
    const int tid  = threadIdx.x;
    const int h    = blockIdx.y;
    const int n    = blockIdx.z;
    const int lane = tid & 63;
    const int wv   = tid >> 6;
    const int c    = lane & 15;
    const int g    = lane >> 4;
    const int pixbase = (wv >> 1) * 64;
    const int ocbase  = blockIdx.x * 128 + (wv & 1) * 64;
    const int ocf0    = blockIdx.x * 8 + (wv & 1) * 4;
    const size_t pixrow = ((size_t)(n * 130 + h + 1) * 130 + (pixbase + c + 1)) * 256;

    f32x4 acc[4][4];
    #pragma unroll
    for (int m = 0; m < 4; ++m)
        #pragma unroll
        for (int p = 0; p < 4; ++p) acc[m][p] = 0.0f;

    s16x8 a0[4], b0[4], a1[4], b1[4];

#define LOADC(ck, A, B) do {                                                        \
    _Pragma("unroll") for (int p = 0; p < 4; ++p)                                   \
        B[p] = *(const s16x8*)(xb + pixrow + (size_t)(16 * p) * 256 + (ck) * 32 + g * 8); \
    _Pragma("unroll") for (int m = 0; m < 4; ++m)                                   \
        A[m] = *(const s16x8*)(w1pk + ((size_t)((ck) * 16 + ocf0 + m)) * 512 + lane * 8); \
} while (0)
#define MM(A, B)                                                                    \
    _Pragma("unroll") for (int m = 0; m < 4; ++m)                                   \
        _Pragma("unroll") for (int p = 0; p < 4; ++p)                               \
            acc[m][p] = __builtin_amdgcn_mfma_f32_16x16x32_bf16(A[m], B[p], acc[m][p], 0, 0, 0)

    LOADC(0, a0, b0);
    #pragma unroll
    for (int ck = 0; ck < 8; ++ck) {
        if ((ck & 1) == 0) { if (ck < 7) LOADC(ck + 1, a1, b1); MM(a0, b0); }
        else               { if (ck < 7) LOADC(ck + 1, a0, b0); MM(a1, b1); }
    }
#undef LOADC
#undef MM

    #pragma unroll
    for (int m = 0; m < 4; ++m) {
        const int oc4 = ocbase + m * 16 + g * 4;
        const f4v s4 = *(const f4v*)(sc + oc4);
        const f4v b4 = *(const f4v*)(bi + oc4);
        #pragma unroll
        for (int p = 0; p < 4; ++p) {
            const int pix = pixbase + p * 16 + c;
            size_t idx = ((size_t)(n * 130 + h + 1) * 130 + pix + 1) * 256 + oc4;
            u16x4 old = *(const u16x4*)(io + idx);
            u16x4 pk;
            #pragma unroll
            for (int j = 0; j < 4; ++j) {
                float y = acc[m][p][j] * s4[j] + b4[j] + bf2f(old[j]);
                pk[j] = f2bf(fmaxf(y, 0.0f));
            }
            *(u16x4*)(io + idx) = pk;
        }
    }
}

// ---------------------------------------------------------------------------
// in-place cummax along H (128-ch padded NHWC). grid 1024 = n*128 + w, block 128
// ---------------------------------------------------------------------------
template<bool REV>
__global__ __launch_bounds__(128)
void pool_h_k(unsigned short* __restrict__ p)
{
    const int n = blockIdx.x >> 7, w = blockIdx.x & 127, cth = threadIdx.x;
    unsigned short* base = p + (((size_t)n * 130 + 1) * 130 + (w + 1)) * 128 + cth;
    const int stride = 130 * 128;
    float m = -3.402823466e+38f;
    for (int i = 0; i < 128; ++i) {
        int hh = REV ? (127 - i) : i;
        unsigned short* q = base + (size_t)hh * stride;
        m = fmaxf(m, bf2f(*q));
        *q = f2bf(m);
    }
}

// ---------------------------------------------------------------------------
// tdst = cummaxW(lsrc) + tdst (both 128-ch padded NHWC). grid 1024 = n*128+h
// ---------------------------------------------------------------------------
template<bool REV>
__global__ __launch_bounds__(128)
void pool_w_add_k(const unsigned short* __restrict__ lsrc,
                  unsigned short* __restrict__ tdst)
{
    const int n = blockIdx.x >> 7, hh = blockIdx.x & 127, cth = threadIdx.x;
    const size_t rowbase = ((size_t)(n * 130 + hh + 1) * 130) * 128 + cth;
    float m = -3.402823466e+38f;
    for (int i = 0; i < 128; ++i) {
        int w = REV ? (127 - i) : i;
        size_t off = rowbase + (size_t)(w + 1) * 128;
        m = fmaxf(m, bf2f(lsrc[off]));
        tdst[off] = f2bf(m + bf2f(tdst[off]));
    }
}

// ---------------------------------------------------------------------------
// zero the pad ring of a padded NHWC tensor. grid (ceil(516*C/8/256), 8)
// ---------------------------------------------------------------------------
__global__ __launch_bounds__(256)
void padzero_k(unsigned short* __restrict__ t, int C)
{
    int idx = blockIdx.x * 256 + threadIdx.x;
    int n = blockIdx.y;
    int cpu = C >> 3;
    if (idx >= 516 * cpu) return;
    int cell = idx / cpu, cq = idx - cell * cpu;
    int h, w;
    if (cell < 260) { h = (cell < 130) ? -1 : 128; w = (cell % 130) - 1; }
    else { int j = cell - 260; w = (j < 128) ? -1 : 128; h = j & 127; }
    size_t off = (((size_t)n * 130 + h + 1) * 130 + (w + 1)) * C + cq * 8;
    uint4 z; z.x = 0; z.y = 0; z.z = 0; z.w = 0;
    *(uint4*)(t + off) = z;
}

// ---------------------------------------------------------------------------
// x fp32 NCHW -> bf16 NHWC padded interior. grid (128 h, 8 n), block 256
// ---------------------------------------------------------------------------
__global__ __launch_bounds__(256)
void transform_x_k(const float* __restrict__ x, unsigned short* __restrict__ xb)
{
    __shared__ float sm[64][132];
    const int h = blockIdx.x, n = blockIdx.y, t = threadIdx.x;
    for (int cc0 = 0; cc0 < 256; cc0 += 64) {
        __syncthreads();
        {
            int ci = t >> 7, wi = t & 127;
            #pragma unroll 8
            for (int k = 0; k < 32; ++k)
                sm[ci + 2 * k][wi] = x[((size_t)(n * 256 + cc0 + ci + 2 * k) << 14) + (h << 7) + wi];
        }
        __syncthreads();
        {
            int wi = t >> 1, cq = t & 1;
            unsigned short tmp[32];
            #pragma unroll
            for (int m2 = 0; m2 < 32; ++m2) tmp[m2] = f2bf(sm[cq * 32 + m2][wi]);
            unsigned short* dst = xb + (((size_t)n * 130 + h + 1) * 130 + wi + 1) * 256 + cc0 + cq * 32;
            #pragma unroll
            for (int q = 0; q < 4; ++q) *(uint4*)(dst + q * 8) = *(const uint4*)(tmp + q * 8);
        }
    }
}

// ---------------------------------------------------------------------------
// weight prepack conv3x3: OIHW fp32 -> frag-packed bf16
// frag = (chunk*9+kk)*(COUT/16) + oc>>4 ; lane = (icr>>3)*16 + (oc&15) ; j = icr&7
// ---------------------------------------------------------------------------
__global__ __launch_bounds__(256)
void prepack3_k(const float* __restrict__ w, unsigned short* __restrict__ dst,
                int CIN, int COUT)
{
    int idx = blockIdx.x * 256 + threadIdx.x;
    if (idx >= COUT * CIN * 9) return;
    int kk = idx % 9; int rest = idx / 9;
    int ic = rest % CIN; int oc = rest / CIN;
    float v = w[(size_t)(oc * CIN + ic) * 9 + kk];
    int chunk = ic >> 5, icr = ic & 31, gg = icr >> 3, j = icr & 7;
    int m = oc >> 4, ocr = oc & 15, ln = gg * 16 + ocr;
    size_t off = ((size_t)((chunk * 9 + kk) * (COUT / 16) + m)) * 512 + ln * 8 + j;
    dst[off] = f2bf(v);
}

__global__ __launch_bounds__(256)
void prepack1_k(const float* __restrict__ w, unsigned short* __restrict__ dst)
{
    int idx = blockIdx.x * 256 + threadIdx.x;   // 256*256
    if (idx >= 65536) return;
    int ic = idx & 255, oc = idx >> 8;
    float v = w[oc * 256 + ic];
    int chunk = ic >> 5, icr = ic & 31, gg = icr >> 3, j = icr & 7;
    int m = oc >> 4, ocr = oc & 15, ln = gg * 16 + ocr;
    size_t off = ((size_t)(chunk * 16 + m)) * 512 + ln * 8 + j;
    dst[off] = f2bf(v);
}

// ---------------------------------------------------------------------------
extern "C" void kernel_launch(void* const* d_in, const int* in_sizes, int n_in,
                              void* d_out, int out_size, void* d_ws, size_t ws_size,
                              hipStream_t stream)
{
    const float* x     = (const float*)d_in[0];
    const float* w_t   = (const float*)d_in[1];
    const float* s_t   = (const float*)d_in[2];
    const float* b_t   = (const float*)d_in[3];
    const float* w_l   = (const float*)d_in[4];
    const float* s_l   = (const float*)d_in[5];
    const float* b_l   = (const float*)d_in[6];
    const float* w_b   = (const float*)d_in[7];
    const float* s_b   = (const float*)d_in[8];
    const float* b_b   = (const float*)d_in[9];
    const float* w_r   = (const float*)d_in[10];
    const float* s_r   = (const float*)d_in[11];
    const float* b_r   = (const float*)d_in[12];
    const float* w_tl3 = (const float*)d_in[13];
    const float* s_tl3 = (const float*)d_in[14];
    const float* b_tl3 = (const float*)d_in[15];
    const float* w_br3 = (const float*)d_in[16];
    const float* s_br3 = (const float*)d_in[17];
    const float* b_br3 = (const float*)d_in[18];
    const float* w_tl1 = (const float*)d_in[19];
    const float* s_tl1 = (const float*)d_in[20];
    const float* b_tl1 = (const float*)d_in[21];
    const float* w_br1 = (const float*)d_in[22];
    const float* s_br1 = (const float*)d_in[23];
    const float* b_br1 = (const float*)d_in[24];
    const float* w_tlo = (const float*)d_in[25];
    const float* s_tlo = (const float*)d_in[26];
    const float* b_tlo = (const float*)d_in[27];
    const float* w_bro = (const float*)d_in[28];
    const float* s_bro = (const float*)d_in[29];
    const float* b_bro = (const float*)d_in[30];

    typedef unsigned short ush;
    const size_t T256 = (size_t)8 * 130 * 130 * 256;   // 34,611,200
    const size_t T128 = (size_t)8 * 130 * 130 * 128;   // 17,305,600

    ush* xb = (ush*)d_ws;
    ush* tt = xb + T256;
    ush* bb = tt + T128;
    ush* ll = bb + T128;
    ush* rr = ll + T128;
    ush* wq = rr + T128;
    ush* wp_t   = wq;
    ush* wp_l   = wp_t   + 294912;
    ush* wp_b   = wp_l   + 294912;
    ush* wp_r   = wp_b   + 294912;
    ush* wp_tl3 = wp_r   + 294912;
    ush* wp_br3 = wp_tl3 + 294912;
    ush* wp_tlo = wp_br3 + 294912;
    ush* wp_bro = wp_tlo + 589824;
    ush* wp_tl1 = wp_bro + 589824;
    ush* wp_br1 = wp_tl1 + 65536;
    ush* tl = ll;                                      // 256-ch buffer over l+r

    // weight prepacks
    prepack3_k<<<dim3((294912 + 255) / 256), dim3(256), 0, stream>>>(w_t,   wp_t,   256, 128);
    prepack3_k<<<dim3((294912 + 255) / 256), dim3(256), 0, stream>>>(w_l,   wp_l,   256, 128);
    prepack3_k<<<dim3((294912 + 255) / 256), dim3(256), 0, stream>>>(w_b,   wp_b,   256, 128);
    prepack3_k<<<dim3((294912 + 255) / 256), dim3(256), 0, stream>>>(w_r,   wp_r,   256, 128);
    prepack3_k<<<dim3((294912 + 255) / 256), dim3(256), 0, stream>>>(w_tl3, wp_tl3, 128, 256);
    prepack3_k<<<dim3((294912 + 255) / 256), dim3(256), 0, stream>>>(w_br3, wp_br3, 128, 256);
    prepack3_k<<<dim3((589824 + 255) / 256), dim3(256), 0, stream>>>(w_tlo, wp_tlo, 256, 256);
    prepack3_k<<<dim3((589824 + 255) / 256), dim3(256), 0, stream>>>(w_bro, wp_bro, 256, 256);
    prepack1_k<<<dim3(256), dim3(256), 0, stream>>>(w_tl1, wp_tl1);
    prepack1_k<<<dim3(256), dim3(256), 0, stream>>>(w_br1, wp_br1);

    // pad rings
    padzero_k<<<dim3(66, 8), dim3(256), 0, stream>>>(xb, 256);
    padzero_k<<<dim3(33, 8), dim3(256), 0, stream>>>(tt, 128);
    padzero_k<<<dim3(33, 8), dim3(256), 0, stream>>>(bb, 128);
    padzero_k<<<dim3(33, 8), dim3(256), 0, stream>>>(ll, 128);
    padzero_k<<<dim3(33, 8), dim3(256), 0, stream>>>(rr, 128);

    // x -> bf16 NHWC padded
    transform_x_k<<<dim3(128, 8), dim3(256), 0, stream>>>(x, xb);

    // stage A: four conv3x3 (Cin=256 -> 128, relu); grid.x = 1 octile * 2 wtiles
    conv3_mfma<256, 128, true, false><<<dim3(2, 64, 8), dim3(256), 0, stream>>>(xb, wp_t, s_t, b_t, tt);
    conv3_mfma<256, 128, true, false><<<dim3(2, 64, 8), dim3(256), 0, stream>>>(xb, wp_l, s_l, b_l, ll);
    conv3_mfma<256, 128, true, false><<<dim3(2, 64, 8), dim3(256), 0, stream>>>(xb, wp_b, s_b, b_b, bb);
    conv3_mfma<256, 128, true, false><<<dim3(2, 64, 8), dim3(256), 0, stream>>>(xb, wp_r, s_r, b_r, rr);

    // pools: tt = u1 = revcummaxH(t)+revcummaxW(l); bb = u2 = cummaxH(b)+cummaxW(r)
    pool_h_k<true ><<<dim3(1024), dim3(128), 0, stream>>>(tt);
    pool_h_k<false><<<dim3(1024), dim3(128), 0, stream>>>(bb);
    pool_w_add_k<true ><<<dim3(1024), dim3(128), 0, stream>>>(ll, tt);
    pool_w_add_k<false><<<dim3(1024), dim3(128), 0, stream>>>(rr, bb);

    // tl chain (tl buffer overlays ll+rr, now dead); grid.x = 2 octiles * 2 wtiles
    padzero_k<<<dim3(66, 8), dim3(256), 0, stream>>>(tl, 256);
    conv3_mfma<128, 256, false, false><<<dim3(4, 64, 8), dim3(256), 0, stream>>>(tt, wp_tl3, s_tl3, b_tl3, tl);
    conv1_mfma<<<dim3(2, 128, 8), dim3(256), 0, stream>>>(xb, wp_tl1, s_tl1, b_tl1, tl);
    conv3_mfma<256, 256, true, true><<<dim3(4, 64, 8), dim3(256), 0, stream>>>(tl, wp_tlo, s_tlo, b_tlo, d_out);

    // br chain (reuses tl buffer; pads still zero)
    conv3_mfma<128, 256, false, false><<<dim3(4, 64, 8), dim3(256), 0, stream>>>(bb, wp_br3, s_br3, b_br3, tl);
    conv1_mfma<<<dim3(2, 128, 8), dim3(256), 0, stream>>>(xb, wp_br1, s_br1, b_br1, tl);
    conv3_mfma<256, 256, true, true><<<dim3(4, 64, 8), dim3(256), 0, stream>>>(tl, wp_bro, s_bro, b_bro,
                                                                               (float*)d_out + 33554432);
}